// Round 17
// baseline (78.780 us; speedup 1.0000x reference)
//
#include <hip/hip_runtime.h>
#include <math.h>

#define EPS 1e-6f

constexpr int B_ = 32;
constexpr int T_ = 8192;
constexpr int F_ = 128;
constexpr int FG = F_ / 4;    // 32 float4 feature-groups per row

// fast pow for strictly-positive base
__device__ __forceinline__ float fpow(float b, float e) {
    return exp2f(e * __log2f(b));
}

// -------- pass 1 (unchanged): per-chunk local sums --------
template<int NC>
__global__ __launch_bounds__(256) void pcen_pass1(
    const float4* __restrict__ x4,
    const float*  __restrict__ log_s,
    float4* __restrict__ S4)
{
    constexpr int L = T_ / NC;
    const int fg    = threadIdx.x & 31;
    const int slot  = threadIdx.x >> 5;              // 0..7
    const int cb    = blockIdx.x % (NC / 8);
    const int b     = blockIdx.x / (NC / 8);
    const int chunk = cb * 8 + slot;

    const float4 lsv = reinterpret_cast<const float4*>(log_s)[fg];
    const float s0 = expf(lsv.x), s1 = expf(lsv.y), s2 = expf(lsv.z), s3 = expf(lsv.w);
    const float a0 = 1.f - s0,   a1 = 1.f - s1,    a2 = 1.f - s2,    a3 = 1.f - s3;

    const float4* xp = x4 + ((size_t)b * T_ + (size_t)chunk * L) * FG + fg;

    float c0 = 0.f, c1 = 0.f, c2 = 0.f, c3 = 0.f;
    #pragma unroll
    for (int i = 0; i < L; ++i) {
        const float4 xv = xp[(size_t)i * FG];
        c0 = fmaf(a0, c0, s0 * xv.x);
        c1 = fmaf(a1, c1, s1 * xv.y);
        c2 = fmaf(a2, c2, s2 * xv.z);
        c3 = fmaf(a3, c3, s3 * xv.w);
    }
    S4[((size_t)b * NC + chunk) * FG + fg] = make_float4(c0, c1, c2, c3);
}

// -------- pass 3: windowed-lookback carry + recurrence + y --------
// float4 lanes (4 independent feature chains/thread), batch-4 (64B in flight)
template<int NC>
__global__ __launch_bounds__(256) void pcen_pass3(
    const float4* __restrict__ x4,
    const float4* __restrict__ state4,
    const float*  __restrict__ log_s,
    const float*  __restrict__ log_alpha,
    const float*  __restrict__ log_delta,
    const float*  __restrict__ log_r,
    const float4* __restrict__ S4,       // [B][NC][FG] local sums from pass1
    float4* __restrict__ y4,
    float4* __restrict__ ns4)
{
    constexpr int L = T_ / NC;            // 32
    const int fg    = threadIdx.x & 31;   // float4 feature group 0..31
    const int slot  = threadIdx.x >> 5;   // 0..7 chunk slot
    const int cb    = blockIdx.x % (NC / 8);
    const int b     = blockIdx.x / (NC / 8);
    const int chunk = cb * 8 + slot;

    const float4 lsv = reinterpret_cast<const float4*>(log_s)[fg];
    const float s0 = expf(lsv.x), s1 = expf(lsv.y), s2 = expf(lsv.z), s3 = expf(lsv.w);
    const float a0 = 1.f - s0,   a1 = 1.f - s1,    a2 = 1.f - s2,    a3 = 1.f - s3;
    const float aL0 = fpow(a0, (float)L);
    const float aL1 = fpow(a1, (float)L);
    const float aL2 = fpow(a2, (float)L);
    const float aL3 = fpow(a3, (float)L);

    // ---- windowed lookback: carry into this chunk ----
    float c0 = 0.f, c1 = 0.f, c2 = 0.f, c3 = 0.f;
    {
        float k0 = 1.f, k1 = 1.f, k2 = 1.f, k3 = 1.f;
        int k = chunk - 1;
        for (; k >= 0; --k) {
            if (k0 < 1e-7f && k1 < 1e-7f && k2 < 1e-7f && k3 < 1e-7f) break;
            const float4 Sv = S4[((size_t)b * NC + k) * FG + fg];
            c0 = fmaf(k0, Sv.x, c0);
            c1 = fmaf(k1, Sv.y, c1);
            c2 = fmaf(k2, Sv.z, c2);
            c3 = fmaf(k3, Sv.w, c3);
            k0 *= aL0; k1 *= aL1; k2 *= aL2; k3 *= aL3;
        }
        if (k < 0) {   // reached t=0 with live coefficient: include true state
            const float4 st = state4[(size_t)b * FG + fg];
            c0 = fmaf(k0, st.x, c0);
            c1 = fmaf(k1, st.y, c1);
            c2 = fmaf(k2, st.z, c2);
            c3 = fmaf(k3, st.w, c3);
        }
    }

    // ---- y parameters ----
    const float4 lav = reinterpret_cast<const float4*>(log_alpha)[fg];
    const float4 ldv = reinterpret_cast<const float4*>(log_delta)[fg];
    const float4 lrv = reinterpret_cast<const float4*>(log_r)[fg];
    const float na0 = -expf(lav.x), na1 = -expf(lav.y), na2 = -expf(lav.z), na3 = -expf(lav.w);
    const float d0 = expf(ldv.x), d1 = expf(ldv.y), d2 = expf(ldv.z), d3 = expf(ldv.w);
    const float r0 = expf(lrv.x), r1 = expf(lrv.y), r2 = expf(lrv.z), r3 = expf(lrv.w);
    const float dr0 = fpow(d0, r0), dr1 = fpow(d1, r1);
    const float dr2 = fpow(d2, r2), dr3 = fpow(d3, r3);

    const size_t base = ((size_t)b * T_ + (size_t)chunk * L) * FG + fg;
    const float4* xp = x4 + base;
    float4*       yp = y4 + base;

    // batch-4 float4: 4 x 16B loads in flight; 4 independent feature chains
    #pragma unroll
    for (int i = 0; i < L; i += 4) {
        float4 xv[4];
        #pragma unroll
        for (int j = 0; j < 4; ++j) xv[j] = xp[(size_t)(i + j) * FG];

        float4 yv[4];
        #pragma unroll
        for (int j = 0; j < 4; ++j) {
            c0 = fmaf(a0, c0, s0 * xv[j].x);
            c1 = fmaf(a1, c1, s1 * xv[j].y);
            c2 = fmaf(a2, c2, s2 * xv[j].z);
            c3 = fmaf(a3, c3, s3 * xv[j].w);
            yv[j].x = exp2f(r0 * __log2f(fmaf(xv[j].x, exp2f(na0 * __log2f(EPS + c0)), d0))) - dr0;
            yv[j].y = exp2f(r1 * __log2f(fmaf(xv[j].y, exp2f(na1 * __log2f(EPS + c1)), d1))) - dr1;
            yv[j].z = exp2f(r2 * __log2f(fmaf(xv[j].z, exp2f(na2 * __log2f(EPS + c2)), d2))) - dr2;
            yv[j].w = exp2f(r3 * __log2f(fmaf(xv[j].w, exp2f(na3 * __log2f(EPS + c3)), d3))) - dr3;
        }

        #pragma unroll
        for (int j = 0; j < 4; ++j) yp[(size_t)(i + j) * FG] = yv[j];
    }

    // final state: last chunk's stepwise carry IS state at t=T (exact path)
    if (chunk == NC - 1) {
        ns4[(size_t)b * FG + fg] = make_float4(c0, c1, c2, c3);
    }
}

template<int NC>
static void launch_all(const float* x, const float* state,
                       const float* log_s, const float* log_alpha,
                       const float* log_delta, const float* log_r,
                       float* y, float* new_state, float* ws, hipStream_t stream)
{
    const float4* x4 = (const float4*)x;
    float4* S4       = (float4*)ws;      // B*NC*FG float4

    pcen_pass1<NC><<<dim3(B_ * (NC / 8)), dim3(256), 0, stream>>>(x4, log_s, S4);
    pcen_pass3<NC><<<dim3(B_ * (NC / 8)), dim3(256), 0, stream>>>(
        x4, (const float4*)state,
        log_s, log_alpha, log_delta, log_r,
        S4, (float4*)y, (float4*)new_state);
}

extern "C" void kernel_launch(void* const* d_in, const int* in_sizes, int n_in,
                              void* d_out, int out_size, void* d_ws, size_t ws_size,
                              hipStream_t stream)
{
    const float* x         = (const float*)d_in[0];
    const float* state     = (const float*)d_in[1];
    const float* log_s     = (const float*)d_in[2];
    const float* log_alpha = (const float*)d_in[3];
    const float* log_delta = (const float*)d_in[4];
    const float* log_r     = (const float*)d_in[5];

    float* y         = (float*)d_out;
    float* new_state = y + (size_t)B_ * T_ * F_;

    // workspace need: 1 buffer of B*NC*F floats
    const size_t need256 = (size_t)B_ * 256 * F_ * sizeof(float);   // 4 MB
    const size_t need128 = (size_t)B_ * 128 * F_ * sizeof(float);   // 2 MB
    if (ws_size >= need256) {
        launch_all<256>(x, state, log_s, log_alpha, log_delta, log_r,
                        y, new_state, (float*)d_ws, stream);
    } else if (ws_size >= need128) {
        launch_all<128>(x, state, log_s, log_alpha, log_delta, log_r,
                        y, new_state, (float*)d_ws, stream);
    } else {
        launch_all<64>(x, state, log_s, log_alpha, log_delta, log_r,
                       y, new_state, (float*)d_ws, stream);
    }
}